// Round 6
// baseline (391.995 us; speedup 1.0000x reference)
//
#include <hip/hip_runtime.h>

// CascadedAttentionCell: B=64, T=512, D=1024, OUT=1024 (all fp32 in/out)
// R6: VMEM-bandwidth model (R5 post-mortem): 768 B/MFMA through L1 (~64 B/cyc/CU
// ceiling) was the 30%-MfmaUtil wall; prefetch depth irrelevant. New GEMM:
// rt=4 x ct=2 wave tiles, 512-thr blocks (8 waves, 2/SIMD), A-frags staged in
// LDS (shared x8 waves, no cvt -- already fp16-packed) -> VMEM 256 B/MFMA (B
// only, 32 B/cyc/CU), LDS 512 B/MFMA (64 B/cyc/CU < 85 ceiling). One barrier
// per 8 k-steps. k_pack_a inverted: coalesced writes, L2-absorbed reads.

typedef _Float16 h8 __attribute__((ext_vector_type(8)));
typedef float f16v __attribute__((ext_vector_type(16)));

__device__ __forceinline__ float tanh_fast(float x) {
    float e = __expf(2.0f * x);
    return 1.0f - 2.0f * __builtin_amdgcn_rcpf(e + 1.0f);
}

// ---- pack Ua (fp32 [K=1024][N=1024]) into fp16 B-fragment order ----
__global__ __launch_bounds__(256) void k_pack_ua(const float* __restrict__ Ua,
                                                 _Float16* __restrict__ B16) {
    int t = blockIdx.x * 256 + threadIdx.x;   // 0..131071
    int nn = t & 31, kg = (t >> 5) & 1, ks = (t >> 6) & 63, nt = t >> 12;
    int n = (nt << 5) + nn;
    int kbase = (ks << 4) + (kg << 3);
    h8 v;
#pragma unroll
    for (int j = 0; j < 8; ++j) v[j] = (_Float16)Ua[(size_t)(kbase + j) * 1024 + n];
    *(h8*)(B16 + ((size_t)t << 3)) = v;
}

// ---- pack inputs into fp16 A-fragment order: coalesced WRITES ----
// Block bx: rows [bx*32,+32), out region A8[bx*4096 .. +4096). Thread t writes
// 16 consecutive-by-wave h8 (16B) slots; reads are 32B pieces, L2-absorbed
// (block footprint 128 KB contiguous).
__global__ __launch_bounds__(256) void k_pack_a(const float* __restrict__ inputs,
                                                _Float16* __restrict__ A16) {
    const int bx = blockIdx.x, t = threadIdx.x;
    h8* dst = (h8*)A16 + ((size_t)bx << 12);
    const float* src = inputs + ((size_t)bx << 15);
#pragma unroll
    for (int i = 0; i < 16; ++i) {
        int p = (i << 8) + t;              // 0..4095
        int ks = p >> 6, l = p & 63;
        int row = l & 31;
        int k = (ks << 4) + ((l >> 5) << 3);
        const float4* s = (const float4*)(src + ((size_t)row << 10) + k);
        float4 v0 = s[0], v1 = s[1];
        dst[p] = (h8){ (_Float16)v0.x, (_Float16)v0.y, (_Float16)v0.z, (_Float16)v0.w,
                       (_Float16)v1.x, (_Float16)v1.y, (_Float16)v1.z, (_Float16)v1.w };
    }
}

// ---- WaS partials, Wa-slice-in-registers (grid 32) ----
__global__ __launch_bounds__(256) void k_was_part(const float* __restrict__ ps,
                                                  const float* __restrict__ Wa,
                                                  float* __restrict__ part) {
    int ic = blockIdx.x >> 2, psl = blockIdx.x & 3;
    int tid = threadIdx.x, wv = tid >> 6, lane = tid & 63;
    int p4 = psl * 64 + lane;
    const float4* Wa4 = (const float4*)Wa;
    float4* part4 = (float4*)part;
#pragma unroll 1
    for (int c = 0; c < 4; ++c) {
        int o0 = ic * 128 + c * 32;
        float4 w[32];
#pragma unroll
        for (int o = 0; o < 32; ++o) w[o] = Wa4[(size_t)(o0 + o) * 256 + p4];
#pragma unroll 1
        for (int bb = 0; bb < 16; ++bb) {
            int b = wv * 16 + bb;
            const float* psb = ps + b * 1024 + o0;
            size_t oidx = (size_t)((ic << 6) + b) * 256 + p4;
            float4 a;
            if (c == 0) { a.x = a.y = a.z = a.w = 0.f; }
            else        { a = part4[oidx]; }
#pragma unroll
            for (int o = 0; o < 32; ++o) {
                float s = psb[o];
                a.x += s * w[o].x; a.y += s * w[o].y;
                a.z += s * w[o].z; a.w += s * w[o].w;
            }
            part4[oidx] = a;
        }
    }
}

// ---- wsWaS[b][p] = Ba[p] + sum_ic part ----
__global__ __launch_bounds__(256) void k_was_reduce(const float* __restrict__ part,
                                                    const float* __restrict__ Ba,
                                                    float* __restrict__ wsWaS) {
    int b = blockIdx.x, tid = threadIdx.x;
    const float4* p4 = (const float4*)part;
    float4 acc = ((const float4*)Ba)[tid];
#pragma unroll
    for (int ic = 0; ic < 8; ++ic) {
        float4 v = p4[((ic << 6) + b) * 256 + tid];
        acc.x += v.x; acc.y += v.y; acc.z += v.z; acc.w += v.w;
    }
    ((float4*)wsWaS)[b * 256 + tid] = acc;
}

// ---- fused GEMM v2: 512 thr (8 waves), 128 rows/block, A via LDS ----
// Per pass (2): wave wv covers cols [ (pass*16+wv*2)*32, +64 ). Per k-chunk
// (128 k): stage 32 A-frags (32 KB) into LDS double-buffer; 8 k-steps each:
// 4 ds_read_b128 (A bands) + 2 B-frag VMEM (depth-1 ring) + 8 MFMAs.
__global__ __launch_bounds__(512, 2) void k_fused_gemm(
    const _Float16* __restrict__ A16, const _Float16* __restrict__ B16,
    const float* __restrict__ wsWaS, const float* __restrict__ Va,
    float* __restrict__ scores)
{
    __shared__ uint4 Albuf[2][2048];     // 64 KB: [buf][(band*8+ks8)*64+lane]
    __shared__ float scoreSh[128];
    const int tid = threadIdx.x;
    const int lane = tid & 63, wv = tid >> 6;
    const int l31 = lane & 31, lhi = lane >> 5;
    const int r0 = blockIdx.x * 128;
    const int b = r0 >> 9;
    const uint4* Ag = (const uint4*)A16 + ((size_t)blockIdx.x << 14);  // block's 4 bands
    const h8* B8 = (const h8*)B16;

    if (tid < 128) scoreSh[tid] = 0.0f;

    for (int pass = 0; pass < 2; ++pass) {
        const int ntb = (pass << 4) + (wv << 1);
        const h8* bBase = B8 + ((size_t)ntb << 12) + lane;

        f16v acc[4][2];
#pragma unroll
        for (int rt = 0; rt < 4; ++rt)
#pragma unroll
            for (int ct = 0; ct < 2; ++ct)
#pragma unroll
                for (int e = 0; e < 16; ++e) acc[rt][ct][e] = 0.0f;

        // stage chunk 0
        uint4 vA[4];
#pragma unroll
        for (int i = 0; i < 4; ++i) {
            int p = tid + (i << 9);
            int f = p >> 6, l = p & 63;
            vA[i] = Ag[(((f >> 3) << 12)) + ((f & 7) << 6) + l];
        }
#pragma unroll
        for (int i = 0; i < 4; ++i) Albuf[0][tid + (i << 9)] = vA[i];
        __syncthreads();

        h8 bf[2][2];
#pragma unroll
        for (int ct = 0; ct < 2; ++ct) bf[0][ct] = bBase[ct << 12];

#pragma unroll 1
        for (int kc = 0; kc < 8; ++kc) {
            const int buf = kc & 1;
            if (kc < 7) {   // global loads for next chunk (drain during MFMAs)
                const int kb = (kc + 1) << 3;
#pragma unroll
                for (int i = 0; i < 4; ++i) {
                    int p = tid + (i << 9);
                    int f = p >> 6, l = p & 63;
                    vA[i] = Ag[(((f >> 3) << 12)) + ((kb + (f & 7)) << 6) + l];
                }
            }
#pragma unroll
            for (int ks8 = 0; ks8 < 8; ++ks8) {
                const int ks = (kc << 3) + ks8;
                const int cur = ks & 1, nxt = cur ^ 1;
                h8 af[4];
#pragma unroll
                for (int rt = 0; rt < 4; ++rt)
                    af[rt] = *(const h8*)&Albuf[buf][((rt << 3) + ks8) * 64 + lane];
                if (ks < 63) {
                    const int o = (ks + 1) << 6;
#pragma unroll
                    for (int ct = 0; ct < 2; ++ct)
                        bf[nxt][ct] = bBase[(ct << 12) + o];
                }
#pragma unroll
                for (int rt = 0; rt < 4; ++rt)
#pragma unroll
                    for (int ct = 0; ct < 2; ++ct)
                        acc[rt][ct] = __builtin_amdgcn_mfma_f32_32x32x16_f16(
                            af[rt], bf[cur][ct], acc[rt][ct], 0, 0, 0);
            }
            if (kc < 7) {
#pragma unroll
                for (int i = 0; i < 4; ++i) Albuf[buf ^ 1][tid + (i << 9)] = vA[i];
            }
            __syncthreads();
        }

        // epilogue: tanh + Va dot over this wave's 64 cols
        float wsv[2], vav[2];
#pragma unroll
        for (int ct = 0; ct < 2; ++ct) {
            int n = ((ntb + ct) << 5) | l31;
            wsv[ct] = wsWaS[b * 1024 + n];
            vav[ct] = Va[n];
        }
#pragma unroll
        for (int rt = 0; rt < 4; ++rt) {
#pragma unroll
            for (int i = 0; i < 16; ++i) {
                float s = tanh_fast(acc[rt][0][i] + wsv[0]) * vav[0]
                        + tanh_fast(acc[rt][1][i] + wsv[1]) * vav[1];
                s += __shfl_xor(s, 1);
                s += __shfl_xor(s, 2);
                s += __shfl_xor(s, 4);
                s += __shfl_xor(s, 8);
                s += __shfl_xor(s, 16);
                if (l31 == 0) {
                    // 32x32 C/D: row=(reg&3)+8*(reg>>2)+4*(lane>>5)  [m74/m101]
                    int row = (rt << 5) + (i & 3) + ((i >> 2) << 3) + (lhi << 2);
                    atomicAdd(&scoreSh[row], s);
                }
            }
        }
    }
    __syncthreads();
    if (tid < 128) scores[r0 + tid] = fmaxf(scoreSh[tid], 0.0f);
}

// ---- softmax over T=512 per batch ----
__global__ __launch_bounds__(256) void k_softmax(const float* __restrict__ scores,
                                                 float* __restrict__ sm) {
    int b = blockIdx.x, tid = threadIdx.x;
    __shared__ float red[256];
    const float* sb = scores + b * 512;
    float s0 = sb[tid], s1 = sb[tid + 256];
    red[tid] = fmaxf(s0, s1);
    __syncthreads();
    for (int st = 128; st > 0; st >>= 1) {
        if (tid < st) red[tid] = fmaxf(red[tid], red[tid + st]);
        __syncthreads();
    }
    float m = red[0];
    __syncthreads();
    float e0 = __expf(s0 - m), e1 = __expf(s1 - m);
    red[tid] = e0 + e1;
    __syncthreads();
    for (int st = 128; st > 0; st >>= 1) {
        if (tid < st) red[tid] += red[tid + st];
        __syncthreads();
    }
    float inv = 1.0f / red[0];
    sm[b * 512 + tid] = e0 * inv;
    sm[b * 512 + 256 + tid] = e1 * inv;
}

// ---- ctx from packed fp16 A16 ----
__global__ __launch_bounds__(256) void k_ctx(const _Float16* __restrict__ A16,
                                             const float* __restrict__ sm,
                                             float* __restrict__ out) {
    const int bx = blockIdx.x, b = blockIdx.y;
    const int tid = threadIdx.x, wv = tid >> 6, lane = tid & 63;
    const int l31 = lane & 31, lhi = lane >> 5;
    const h8* A8 = (const h8*)A16;
    const int ksl = bx * 4 + wv;
    float facc[8];
#pragma unroll
    for (int j = 0; j < 8; ++j) facc[j] = 0.0f;
    const float* smb = sm + b * 512;
#pragma unroll 4
    for (int rbl = 0; rbl < 16; ++rbl) {
        h8 x = A8[(((size_t)(b * 16 + rbl) << 6) + ksl) * 64 + lane];
        float wgt = smb[rbl * 32 + l31];
#pragma unroll
        for (int j = 0; j < 8; ++j) facc[j] += wgt * (float)x[j];
    }
#pragma unroll
    for (int m = 1; m < 32; m <<= 1)
#pragma unroll
        for (int j = 0; j < 8; ++j) facc[j] += __shfl_xor(facc[j], m);
    if (l31 == 0) {
        int oct = bx * 8 + wv * 2 + lhi;
        float* o = out + b * 1024 + oct * 8;
#pragma unroll
        for (int j = 0; j < 8; ++j) o[j] = facc[j];
    }
}

extern "C" void kernel_launch(void* const* d_in, const int* in_sizes, int n_in,
                              void* d_out, int out_size, void* d_ws, size_t ws_size,
                              hipStream_t stream) {
    const float* inputs = (const float*)d_in[0];
    const float* prev   = (const float*)d_in[1];
    const float* Wa     = (const float*)d_in[2];
    const float* Ua     = (const float*)d_in[3];
    const float* Va     = (const float*)d_in[4];
    const float* Ba     = (const float*)d_in[5];
    float* out = (float*)d_out;

    char* ws = (char*)d_ws;
    _Float16* A16   = (_Float16*)(ws);                         // 64 MB packed A
    _Float16* B16   = (_Float16*)(ws + (64u << 20));           // 2 MB packed Ua
    float* wasPart  = (float*)(ws + (66u << 20));              // 2 MB
    float* wsWaS    = (float*)(ws + (68u << 20));              // 256 KB
    float* scores   = (float*)(ws + (68u << 20) + (256u << 10));   // 128 KB
    float* sm       = (float*)(ws + (68u << 20) + (384u << 10));   // 128 KB

    hipLaunchKernelGGL(k_pack_ua,    dim3(512),    dim3(256), 0, stream, Ua, B16);
    hipLaunchKernelGGL(k_pack_a,     dim3(1024),   dim3(256), 0, stream, inputs, A16);
    hipLaunchKernelGGL(k_was_part,   dim3(32),     dim3(256), 0, stream, prev, Wa, wasPart);
    hipLaunchKernelGGL(k_was_reduce, dim3(64),     dim3(256), 0, stream, wasPart, Ba, wsWaS);
    hipLaunchKernelGGL(k_fused_gemm, dim3(256),    dim3(512), 0, stream, A16, B16, wsWaS, Va, scores);
    hipLaunchKernelGGL(k_softmax,    dim3(64),     dim3(256), 0, stream, scores, sm);
    hipLaunchKernelGGL(k_ctx,        dim3(16, 64), dim3(256), 0, stream, A16, sm, out);
}